// Round 8
// baseline (171.768 us; speedup 1.0000x reference)
//
#include <hip/hip_runtime.h>
#include <cstddef>

#define NUM_TYPES 4
#define NUM_CH    64
#define TBL_ROWS  256                    // 16 classes x 16 slo values (slo in [-5..10])
#define ROW_F32   192                    // [T0(64) | TC(64) | TS(64)]

typedef float    vfloat4 __attribute__((ext_vector_type(4)));
typedef unsigned vuint2  __attribute__((ext_vector_type(2)));

// ---- kernel 1: fused {factorized table build} + {per-edge meta} ----
// b_s(t) = cos^2(pi/2*(t-s)/6) = 1/2 + 1/2*cos(theta - i*pi/6), theta = pi*(t-slo)/6
// => out = T0 + cos(theta)*TC + sin(theta)*TS, tables indexed by (cls, slo).
__global__ __launch_bounds__(256)
void meta_table_kernel(const int* __restrict__ atom_types,
                       const int* __restrict__ edge_src,
                       const int* __restrict__ edge_dst,
                       const float* __restrict__ norm_length,
                       const float* __restrict__ W,
                       float* __restrict__ T,
                       unsigned* __restrict__ meta,   // uint2 stream, stored nt
                       int n_edges, int n_pad)
{
    // blocks 0..63: build the 256x192 table (one element per thread)
    if (blockIdx.x < 64) {
        const float COS6[12] = {1.f, 0.8660254038f, 0.5f, 0.f, -0.5f, -0.8660254038f,
                                -1.f, -0.8660254038f, -0.5f, 0.f, 0.5f, 0.8660254038f};
        const float SIN6[12] = {0.f, 0.5f, 0.8660254038f, 1.f, 0.8660254038f, 0.5f,
                                0.f, -0.5f, -0.8660254038f, -1.f, -0.8660254038f, -0.5f};
        const int gid = blockIdx.x * 256 + threadIdx.x;   // 0..16383
        const int c   = gid & 63;
        const int row = gid >> 6;
        const int slo = (row & 15) - 5;
        const int cls = row >> 4;

        float s0 = 0.f, sc = 0.f, ss = 0.f;
        #pragma unroll
        for (int i = 0; i < 12; ++i) {
            const int s = slo + i;
            if (s >= 0 && s < 16) {
                const float w = W[((cls << 4) + s) * NUM_CH + c];
                s0 += w;
                sc = fmaf(w, COS6[i], sc);
                ss = fmaf(w, SIN6[i], ss);
            }
        }
        float* r = T + row * ROW_F32;
        r[c]       = 0.5f * s0;
        r[64 + c]  = 0.5f * sc;
        r[128 + c] = 0.5f * ss;
    }

    // all blocks: per-edge meta (grid-stride), nt-stored
    const int stride = gridDim.x * blockDim.x;
    for (int e = blockIdx.x * blockDim.x + threadIdx.x; e < n_pad; e += stride) {
        vuint2 mv = {0u, 0u};
        if (e < n_edges) {
            const int et  = atom_types[edge_src[e]] * NUM_TYPES + atom_types[edge_dst[e]];
            const float t = norm_length[e] * 15.0f;          // t = x/h, h = 1/15
            const int slo = (int)t - 5;                      // in [-5..10]
            mv.x = (unsigned)((et << 4) + slo + 5);          // table row 0..255
            mv.y = __float_as_uint((t - (float)slo) * (1.0f / 12.0f));  // theta (revs)
        }
        __builtin_nontemporal_store(mv, reinterpret_cast<vuint2*>(meta + 2 * (size_t)e));
    }
}

// ---- kernel 2: pure stream: meta -> table -> nt-store out ----
__global__ __launch_bounds__(256, 4)
void spline_eval_kernel(const uint2* __restrict__ meta,
                        const float4* __restrict__ tbl,
                        float* __restrict__ out,
                        int n_edges)
{
    const int lane = threadIdx.x & 63;
    const int g    = lane >> 4;          // edge-in-step 0..3
    const int q    = lane & 15;          // channel quad: channels q*4..q*4+3

    const int waves_per_block = blockDim.x >> 6;
    const int gwave  = blockIdx.x * waves_per_block + (threadIdx.x >> 6);
    const int nwaves = gridDim.x * waves_per_block;
    const int nchunks = (n_edges + 63) >> 6;

    for (int chunk = gwave; chunk < nchunks; chunk += nwaves) {
        const int e0 = chunk << 6;
        const uint2* mp = meta + e0;

        if (e0 + 64 <= n_edges) {
            // ---- fast path: full chunk, no per-store guard ----
            #pragma unroll 4
            for (int k = 0; k < 16; ++k) {
                const int idx = (k << 2) + g;
                const uint2 m = mp[idx];
                const float r = __uint_as_float(m.y);

                float cs, sn;
                asm("v_cos_f32 %0, %1" : "=v"(cs) : "v"(r));
                asm("v_sin_f32 %0, %1" : "=v"(sn) : "v"(r));

                const float4* rp = tbl + ((int)m.x * 48 + q);
                const float4 a = rp[0];     // T0
                const float4 b = rp[16];    // TC
                const float4 c = rp[32];    // TS

                vfloat4 o;
                o.x = fmaf(sn, c.x, fmaf(cs, b.x, a.x));
                o.y = fmaf(sn, c.y, fmaf(cs, b.y, a.y));
                o.z = fmaf(sn, c.z, fmaf(cs, b.z, a.z));
                o.w = fmaf(sn, c.w, fmaf(cs, b.w, a.w));

                vfloat4* po = reinterpret_cast<vfloat4*>(
                    out + (size_t)(e0 + idx) * NUM_CH + (q << 2));
                __builtin_nontemporal_store(o, po);
            }
        } else {
            // ---- tail chunk: guarded stores ----
            #pragma unroll 4
            for (int k = 0; k < 16; ++k) {
                const int idx = (k << 2) + g;
                const int e   = e0 + idx;
                const uint2 m = mp[idx];
                const float r = __uint_as_float(m.y);

                float cs, sn;
                asm("v_cos_f32 %0, %1" : "=v"(cs) : "v"(r));
                asm("v_sin_f32 %0, %1" : "=v"(sn) : "v"(r));

                const float4* rp = tbl + ((int)m.x * 48 + q);
                const float4 a = rp[0];
                const float4 b = rp[16];
                const float4 c = rp[32];

                vfloat4 o;
                o.x = fmaf(sn, c.x, fmaf(cs, b.x, a.x));
                o.y = fmaf(sn, c.y, fmaf(cs, b.y, a.y));
                o.z = fmaf(sn, c.z, fmaf(cs, b.z, a.z));
                o.w = fmaf(sn, c.w, fmaf(cs, b.w, a.w));

                if (e < n_edges) {
                    vfloat4* po = reinterpret_cast<vfloat4*>(
                        out + (size_t)e * NUM_CH + (q << 2));
                    __builtin_nontemporal_store(o, po);
                }
            }
        }
    }
}

extern "C" void kernel_launch(void* const* d_in, const int* in_sizes, int n_in,
                              void* d_out, int out_size, void* d_ws, size_t ws_size,
                              hipStream_t stream)
{
    const int*   atom_types   = (const int*)d_in[0];
    const int*   edge_index   = (const int*)d_in[1];
    const float* norm_length  = (const float*)d_in[2];
    const float* class_weight = (const float*)d_in[3];
    float*       out          = (float*)d_out;

    const int n_edges   = in_sizes[2];           // |norm_length| = E
    const int* edge_src = edge_index;            // row 0 of [2, E]
    const int* edge_dst = edge_index + n_edges;  // row 1

    const int nchunks = (n_edges + 63) >> 6;
    const int n_pad   = nchunks << 6;

    float*    tbl  = (float*)d_ws;                        // 192 KB table
    unsigned* meta = (unsigned*)((char*)d_ws + (1 << 20)); // 16 MB packed meta

    hipLaunchKernelGGL(meta_table_kernel, dim3(2048), dim3(256), 0, stream,
                       atom_types, edge_src, edge_dst, norm_length,
                       class_weight, tbl, meta, n_edges, n_pad);
    hipLaunchKernelGGL(spline_eval_kernel, dim3(4096), dim3(256), 0, stream,
                       (const uint2*)meta, (const float4*)tbl, out, n_edges);
}

// Round 9
// 127.939 us; speedup vs baseline: 1.3426x; 1.3426x over previous
//
#include <hip/hip_runtime.h>
#include <cstddef>

#define NUM_TYPES 4
#define NUM_CH    64
#define TBL_ROWS  256                    // 16 classes x 16 slo values (slo in [-5..10])
#define ROW_F32   192                    // [T0(64) | TC(64) | TS(64)]

typedef float vfloat4 __attribute__((ext_vector_type(4)));   // native vec for nt-store

// ---- kernel 1: factorized table T[cls][slo+5] = {T0, TC, TS} ----
// b_s(t) = cos^2(pi/2*(t-s)/6) = 1/2 + 1/2*cos(theta - i*pi/6), theta = pi*(t-slo)/6
// => out = T0 + cos(theta)*TC + sin(theta)*TS
__global__ void build_table_kernel(const float* __restrict__ W,
                                   float* __restrict__ T)
{
    const float COS6[12] = {1.f, 0.8660254038f, 0.5f, 0.f, -0.5f, -0.8660254038f,
                            -1.f, -0.8660254038f, -0.5f, 0.f, 0.5f, 0.8660254038f};
    const float SIN6[12] = {0.f, 0.5f, 0.8660254038f, 1.f, 0.8660254038f, 0.5f,
                            0.f, -0.5f, -0.8660254038f, -1.f, -0.8660254038f, -0.5f};
    const int gid = blockIdx.x * blockDim.x + threadIdx.x;
    if (gid >= TBL_ROWS * NUM_CH) return;
    const int c   = gid & 63;
    const int row = gid >> 6;
    const int slo = (row & 15) - 5;
    const int cls = row >> 4;

    float s0 = 0.f, sc = 0.f, ss = 0.f;
    #pragma unroll
    for (int i = 0; i < 12; ++i) {
        const int s = slo + i;
        if (s >= 0 && s < 16) {
            const float w = W[((cls << 4) + s) * NUM_CH + c];
            s0 += w;
            sc = fmaf(w, COS6[i], sc);
            ss = fmaf(w, SIN6[i], ss);
        }
    }
    float* r = T + row * ROW_F32;
    r[c]       = 0.5f * s0;
    r[64 + c]  = 0.5f * sc;
    r[128 + c] = 0.5f * ss;
}

// ---- kernel 2 (phase A): per-edge meta -> packed {row, theta_revs} ----
// Normal (cached) stores: phase B re-reads this from L2.
__global__ __launch_bounds__(256)
void edge_meta_kernel(const int* __restrict__ atom_types,
                      const int* __restrict__ edge_src,
                      const int* __restrict__ edge_dst,
                      const float* __restrict__ norm_length,
                      uint2* __restrict__ meta,
                      int n_edges, int n_pad)
{
    const int stride = gridDim.x * blockDim.x;
    for (int e = blockIdx.x * blockDim.x + threadIdx.x; e < n_pad; e += stride) {
        uint2 mv = {0u, 0u};
        if (e < n_edges) {
            const int et  = atom_types[edge_src[e]] * NUM_TYPES + atom_types[edge_dst[e]];
            const float t = norm_length[e] * 15.0f;          // t = x/h, h = 1/15
            const int slo = (int)t - 5;                      // in [-5..10]
            mv.x = (unsigned)((et << 4) + slo + 5);          // table row 0..255
            mv.y = __float_as_uint((t - (float)slo) * (1.0f / 12.0f));  // theta (revs)
        }
        meta[e] = mv;
    }
}

// ---- kernel 3 (phase B): pure stream, software-rotated ----
// Changes vs R7: (1) one coalesced 8B meta load per lane per chunk,
// redistributed via __shfl (lgkmcnt domain, off the vmcnt path);
// (2) step k+1's table loads are issued BEFORE step k's nt stores, so
// load-waits never drain fresh store acks (in-order vmcnt chaining).
__global__ __launch_bounds__(256, 4)
void spline_eval_kernel(const uint2* __restrict__ meta,
                        const float4* __restrict__ tbl,
                        float* __restrict__ out,
                        int n_edges)
{
    const int lane = threadIdx.x & 63;
    const int g    = lane >> 4;          // edge-in-step 0..3
    const int q    = lane & 15;          // channel quad: channels q*4..q*4+3

    const int waves_per_block = blockDim.x >> 6;
    const int gwave  = blockIdx.x * waves_per_block + (threadIdx.x >> 6);
    const int nwaves = gridDim.x * waves_per_block;
    const int nchunks = (n_edges + 63) >> 6;

    for (int chunk = gwave; chunk < nchunks; chunk += nwaves) {
        const int e0 = chunk << 6;

        // whole chunk's meta in ONE coalesced load (array padded to n_pad)
        const uint2 my = meta[e0 + lane];

        // prologue: step 0 operands
        unsigned mrow = __shfl(my.x, g);
        float    mth  = __uint_as_float(__shfl((int)my.y, g));
        {
            const float4* rp = tbl + ((int)mrow * 48 + q);
            // initial loads issued here; waited on at first use below
            asm volatile("" ::: "memory");
        }
        const float4* rp0 = tbl + ((int)mrow * 48 + q);
        float4 a = rp0[0], b = rp0[16], c = rp0[32];

        #pragma unroll 2
        for (int k = 0; k < 16; ++k) {
            const int e  = e0 + (k << 2) + g;
            const float th = mth;
            const float4 ca = a, cb = b, cc = c;

            // rotate: issue NEXT step's loads before this step's store
            if (k < 15) {
                const int nidx = ((k + 1) << 2) + g;
                mrow = __shfl(my.x, nidx);
                mth  = __uint_as_float(__shfl((int)my.y, nidx));
                const float4* np = tbl + ((int)mrow * 48 + q);
                a = np[0]; b = np[16]; c = np[32];
            }

            float cs, sn;
            asm("v_cos_f32 %0, %1" : "=v"(cs) : "v"(th));
            asm("v_sin_f32 %0, %1" : "=v"(sn) : "v"(th));

            vfloat4 o;
            o.x = fmaf(sn, cc.x, fmaf(cs, cb.x, ca.x));
            o.y = fmaf(sn, cc.y, fmaf(cs, cb.y, ca.y));
            o.z = fmaf(sn, cc.z, fmaf(cs, cb.z, ca.z));
            o.w = fmaf(sn, cc.w, fmaf(cs, cb.w, ca.w));

            if (e < n_edges) {
                vfloat4* po = reinterpret_cast<vfloat4*>(
                    out + (size_t)e * NUM_CH + (q << 2));
                __builtin_nontemporal_store(o, po);   // out is never re-read
            }
        }
    }
}

extern "C" void kernel_launch(void* const* d_in, const int* in_sizes, int n_in,
                              void* d_out, int out_size, void* d_ws, size_t ws_size,
                              hipStream_t stream)
{
    const int*   atom_types   = (const int*)d_in[0];
    const int*   edge_index   = (const int*)d_in[1];
    const float* norm_length  = (const float*)d_in[2];
    const float* class_weight = (const float*)d_in[3];
    float*       out          = (float*)d_out;

    const int n_edges   = in_sizes[2];           // |norm_length| = E
    const int* edge_src = edge_index;            // row 0 of [2, E]
    const int* edge_dst = edge_index + n_edges;  // row 1

    const int nchunks = (n_edges + 63) >> 6;
    const int n_pad   = nchunks << 6;

    float* tbl  = (float*)d_ws;                           // 192 KB table
    uint2* meta = (uint2*)((char*)d_ws + (1 << 20));      // 16 MB packed meta

    hipLaunchKernelGGL(build_table_kernel, dim3(64), dim3(256), 0, stream,
                       class_weight, tbl);
    hipLaunchKernelGGL(edge_meta_kernel, dim3(2048), dim3(256), 0, stream,
                       atom_types, edge_src, edge_dst, norm_length,
                       meta, n_edges, n_pad);
    hipLaunchKernelGGL(spline_eval_kernel, dim3(4096), dim3(256), 0, stream,
                       meta, (const float4*)tbl, out, n_edges);
}

// Round 10
// 122.814 us; speedup vs baseline: 1.3986x; 1.0417x over previous
//
#include <hip/hip_runtime.h>
#include <cstddef>

#define NUM_TYPES 4
#define NUM_CH    64
#define TBL_ROWS  256                 // 16 classes x 16 slo values (slo in [-5..10])
#define ROW_U32   96                  // bf16 table: [T0 32w | TC 32w | TS 32w], 384 B/row

typedef float vfloat4 __attribute__((ext_vector_type(4)));   // native vec for nt-store

// round-to-nearest-even f32 -> bf16, packed pair (a=low16, b=high16)
__device__ __forceinline__ unsigned pack_bf16(float a, float b) {
    unsigned ua = __float_as_uint(a);
    unsigned ub = __float_as_uint(b);
    ua += 0x7fffu + ((ua >> 16) & 1u);
    ub += 0x7fffu + ((ub >> 16) & 1u);
    return (ua >> 16) | (ub & 0xffff0000u);
}
__device__ __forceinline__ float bf_lo(unsigned w) { return __uint_as_float(w << 16); }
__device__ __forceinline__ float bf_hi(unsigned w) { return __uint_as_float(w & 0xffff0000u); }

// ---- kernel 1: factorized table (bf16-packed) ----
// b_s(t) = cos^2(pi/2*(t-s)/6) = 1/2 + 1/2*cos(theta - i*pi/6), theta = pi*(t-slo)/6
// => out = T0 + cos(theta)*TC + sin(theta)*TS; one thread per (row, channel-pair).
__global__ void build_table_kernel(const float* __restrict__ W,
                                   unsigned* __restrict__ T)
{
    const float COS6[12] = {1.f, 0.8660254038f, 0.5f, 0.f, -0.5f, -0.8660254038f,
                            -1.f, -0.8660254038f, -0.5f, 0.f, 0.5f, 0.8660254038f};
    const float SIN6[12] = {0.f, 0.5f, 0.8660254038f, 1.f, 0.8660254038f, 0.5f,
                            0.f, -0.5f, -0.8660254038f, -1.f, -0.8660254038f, -0.5f};
    const int gid = blockIdx.x * blockDim.x + threadIdx.x;
    if (gid >= TBL_ROWS * 32) return;        // 32 channel-pairs per row
    const int p   = gid & 31;
    const int row = gid >> 5;
    const int slo = (row & 15) - 5;
    const int cls = row >> 4;
    const int c0  = p << 1;

    float s0a = 0.f, sca = 0.f, ssa = 0.f;
    float s0b = 0.f, scb = 0.f, ssb = 0.f;
    #pragma unroll
    for (int i = 0; i < 12; ++i) {
        const int s = slo + i;
        if (s >= 0 && s < 16) {
            const float wa = W[((cls << 4) + s) * NUM_CH + c0];
            const float wb = W[((cls << 4) + s) * NUM_CH + c0 + 1];
            s0a += wa;  sca = fmaf(wa, COS6[i], sca);  ssa = fmaf(wa, SIN6[i], ssa);
            s0b += wb;  scb = fmaf(wb, COS6[i], scb);  ssb = fmaf(wb, SIN6[i], ssb);
        }
    }
    unsigned* r = T + row * ROW_U32;
    r[p]      = pack_bf16(0.5f * s0a, 0.5f * s0b);
    r[32 + p] = pack_bf16(0.5f * sca, 0.5f * scb);
    r[64 + p] = pack_bf16(0.5f * ssa, 0.5f * ssb);
}

// ---- kernel 2 (phase A): per-edge meta -> packed {row, theta_revs} ----
__global__ __launch_bounds__(256)
void edge_meta_kernel(const int* __restrict__ atom_types,
                      const int* __restrict__ edge_src,
                      const int* __restrict__ edge_dst,
                      const float* __restrict__ norm_length,
                      uint2* __restrict__ meta,
                      int n_edges, int n_pad)
{
    const int stride = gridDim.x * blockDim.x;
    for (int e = blockIdx.x * blockDim.x + threadIdx.x; e < n_pad; e += stride) {
        uint2 mv = {0u, 0u};
        if (e < n_edges) {
            const int et  = atom_types[edge_src[e]] * NUM_TYPES + atom_types[edge_dst[e]];
            const float t = norm_length[e] * 15.0f;          // t = x/h, h = 1/15
            const int slo = (int)t - 5;                      // in [-5..10]
            mv.x = (unsigned)((et << 4) + slo + 5);          // table row 0..255
            mv.y = __float_as_uint((t - (float)slo) * (1.0f / 12.0f));  // theta (revs)
        }
        meta[e] = mv;
    }
}

// ---- kernel 3 (phase B): pure stream: meta -> bf16 table -> nt-store out ----
// Identical structure to the 118.7us R7 kernel; ONLY the table reads changed
// from 3x float4 (48 B/lane) to 3x uint2 bf16-pairs (24 B/lane).
__global__ __launch_bounds__(256, 4)
void spline_eval_kernel(const uint2* __restrict__ meta,
                        const unsigned* __restrict__ tblw,
                        float* __restrict__ out,
                        int n_edges)
{
    const int lane = threadIdx.x & 63;
    const int g    = lane >> 4;          // edge-in-step 0..3
    const int q    = lane & 15;          // channel quad: channels q*4..q*4+3

    const int waves_per_block = blockDim.x >> 6;
    const int gwave  = blockIdx.x * waves_per_block + (threadIdx.x >> 6);
    const int nwaves = gridDim.x * waves_per_block;
    const int nchunks = (n_edges + 63) >> 6;

    for (int chunk = gwave; chunk < nchunks; chunk += nwaves) {
        const int e0 = chunk << 6;
        const uint2* mp = meta + e0;

        #pragma unroll 4
        for (int k = 0; k < 16; ++k) {
            const int idx = (k << 2) + g;
            const int e   = e0 + idx;
            const uint2 m = mp[idx];               // 4 distinct addrs/wave (broadcast)
            const float r = __uint_as_float(m.y);

            float cs, sn;
            asm("v_cos_f32 %0, %1" : "=v"(cs) : "v"(r));
            asm("v_sin_f32 %0, %1" : "=v"(sn) : "v"(r));

            const unsigned* rp = tblw + (int)m.x * ROW_U32 + (q << 1);
            const uint2 a2 = *reinterpret_cast<const uint2*>(rp);        // T0 ch 4q..4q+3
            const uint2 b2 = *reinterpret_cast<const uint2*>(rp + 32);   // TC
            const uint2 c2 = *reinterpret_cast<const uint2*>(rp + 64);   // TS

            vfloat4 o;
            o.x = fmaf(sn, bf_lo(c2.x), fmaf(cs, bf_lo(b2.x), bf_lo(a2.x)));
            o.y = fmaf(sn, bf_hi(c2.x), fmaf(cs, bf_hi(b2.x), bf_hi(a2.x)));
            o.z = fmaf(sn, bf_lo(c2.y), fmaf(cs, bf_lo(b2.y), bf_lo(a2.y)));
            o.w = fmaf(sn, bf_hi(c2.y), fmaf(cs, bf_hi(b2.y), bf_hi(a2.y)));

            if (e < n_edges) {
                vfloat4* po = reinterpret_cast<vfloat4*>(
                    out + (size_t)e * NUM_CH + (q << 2));
                __builtin_nontemporal_store(o, po);   // out is never re-read
            }
        }
    }
}

extern "C" void kernel_launch(void* const* d_in, const int* in_sizes, int n_in,
                              void* d_out, int out_size, void* d_ws, size_t ws_size,
                              hipStream_t stream)
{
    const int*   atom_types   = (const int*)d_in[0];
    const int*   edge_index   = (const int*)d_in[1];
    const float* norm_length  = (const float*)d_in[2];
    const float* class_weight = (const float*)d_in[3];
    float*       out          = (float*)d_out;

    const int n_edges   = in_sizes[2];           // |norm_length| = E
    const int* edge_src = edge_index;            // row 0 of [2, E]
    const int* edge_dst = edge_index + n_edges;  // row 1

    const int nchunks = (n_edges + 63) >> 6;
    const int n_pad   = nchunks << 6;

    unsigned* tbl  = (unsigned*)d_ws;                     // 96 KB bf16 table
    uint2*    meta = (uint2*)((char*)d_ws + (1 << 20));   // 16 MB packed meta

    hipLaunchKernelGGL(build_table_kernel, dim3(32), dim3(256), 0, stream,
                       class_weight, tbl);
    hipLaunchKernelGGL(edge_meta_kernel, dim3(2048), dim3(256), 0, stream,
                       atom_types, edge_src, edge_dst, norm_length,
                       meta, n_edges, n_pad);
    hipLaunchKernelGGL(spline_eval_kernel, dim3(4096), dim3(256), 0, stream,
                       meta, tbl, out, n_edges);
}

// Round 11
// 118.786 us; speedup vs baseline: 1.4460x; 1.0339x over previous
//
#include <hip/hip_runtime.h>
#include <cstddef>

#define NUM_TYPES 4
#define NUM_CH    64
#define TBL_ROWS  256                    // 16 classes x 16 slo values (slo in [-5..10])
#define ROW_F32   192                    // [T0(64) | TC(64) | TS(64)]

typedef float  vfloat4 __attribute__((ext_vector_type(4)));   // native vec for nt-store

// ---- kernel 1: factorized table T[cls][slo+5] = {T0, TC, TS} ----
// b_s(t) = cos^2(pi/2*(t-s)/6) = 1/2 + 1/2*cos(theta - i*pi/6), theta = pi*(t-slo)/6
// => out = T0 + cos(theta)*TC + sin(theta)*TS
__global__ void build_table_kernel(const float* __restrict__ W,
                                   float* __restrict__ T)
{
    const float COS6[12] = {1.f, 0.8660254038f, 0.5f, 0.f, -0.5f, -0.8660254038f,
                            -1.f, -0.8660254038f, -0.5f, 0.f, 0.5f, 0.8660254038f};
    const float SIN6[12] = {0.f, 0.5f, 0.8660254038f, 1.f, 0.8660254038f, 0.5f,
                            0.f, -0.5f, -0.8660254038f, -1.f, -0.8660254038f, -0.5f};
    const int gid = blockIdx.x * blockDim.x + threadIdx.x;
    if (gid >= TBL_ROWS * NUM_CH) return;
    const int c   = gid & 63;
    const int row = gid >> 6;
    const int slo = (row & 15) - 5;
    const int cls = row >> 4;

    float s0 = 0.f, sc = 0.f, ss = 0.f;
    #pragma unroll
    for (int i = 0; i < 12; ++i) {
        const int s = slo + i;
        if (s >= 0 && s < 16) {
            const float w = W[((cls << 4) + s) * NUM_CH + c];
            s0 += w;
            sc = fmaf(w, COS6[i], sc);
            ss = fmaf(w, SIN6[i], ss);
        }
    }
    float* r = T + row * ROW_F32;
    r[c]       = 0.5f * s0;
    r[64 + c]  = 0.5f * sc;
    r[128 + c] = 0.5f * ss;
}

// ---- kernel 2 (phase A): per-edge meta -> packed {row, theta_revs} ----
__global__ __launch_bounds__(256)
void edge_meta_kernel(const int* __restrict__ atom_types,
                      const int* __restrict__ edge_src,
                      const int* __restrict__ edge_dst,
                      const float* __restrict__ norm_length,
                      uint2* __restrict__ meta,
                      int n_edges, int n_pad)
{
    const int stride = gridDim.x * blockDim.x;
    for (int e = blockIdx.x * blockDim.x + threadIdx.x; e < n_pad; e += stride) {
        uint2 mv = {0u, 0u};
        if (e < n_edges) {
            const int et  = atom_types[edge_src[e]] * NUM_TYPES + atom_types[edge_dst[e]];
            const float t = norm_length[e] * 15.0f;          // t = x/h, h = 1/15
            const int slo = (int)t - 5;                      // in [-5..10]
            mv.x = (unsigned)((et << 4) + slo + 5);          // table row 0..255
            mv.y = __float_as_uint((t - (float)slo) * (1.0f / 12.0f));  // theta (revs)
        }
        meta[e] = mv;
    }
}

// ---- kernel 3 (phase B): pure stream: meta -> table -> nt-store out ----
__global__ __launch_bounds__(256, 4)
void spline_eval_kernel(const uint2* __restrict__ meta,
                        const float4* __restrict__ tbl,
                        float* __restrict__ out,
                        int n_edges)
{
    const int lane = threadIdx.x & 63;
    const int g    = lane >> 4;          // edge-in-step 0..3
    const int q    = lane & 15;          // channel quad: channels q*4..q*4+3

    const int waves_per_block = blockDim.x >> 6;
    const int gwave  = blockIdx.x * waves_per_block + (threadIdx.x >> 6);
    const int nwaves = gridDim.x * waves_per_block;
    const int nchunks = (n_edges + 63) >> 6;

    for (int chunk = gwave; chunk < nchunks; chunk += nwaves) {
        const int e0 = chunk << 6;
        const uint2* mp = meta + e0;

        #pragma unroll 4
        for (int k = 0; k < 16; ++k) {
            const int idx = (k << 2) + g;
            const int e   = e0 + idx;
            const uint2 m = mp[idx];               // 4 distinct addrs/wave (broadcast)
            const float r = __uint_as_float(m.y);

            float cs, sn;
            asm("v_cos_f32 %0, %1" : "=v"(cs) : "v"(r));
            asm("v_sin_f32 %0, %1" : "=v"(sn) : "v"(r));

            const float4* rp = tbl + ((int)m.x * 48 + q);
            const float4 a = rp[0];     // T0
            const float4 b = rp[16];    // TC
            const float4 c = rp[32];    // TS

            vfloat4 o;
            o.x = fmaf(sn, c.x, fmaf(cs, b.x, a.x));
            o.y = fmaf(sn, c.y, fmaf(cs, b.y, a.y));
            o.z = fmaf(sn, c.z, fmaf(cs, b.z, a.z));
            o.w = fmaf(sn, c.w, fmaf(cs, b.w, a.w));

            if (e < n_edges) {
                vfloat4* po = reinterpret_cast<vfloat4*>(out + (size_t)e * NUM_CH + (q << 2));
                __builtin_nontemporal_store(o, po);   // bypass L2: out is never re-read
            }
        }
    }
}

extern "C" void kernel_launch(void* const* d_in, const int* in_sizes, int n_in,
                              void* d_out, int out_size, void* d_ws, size_t ws_size,
                              hipStream_t stream)
{
    const int*   atom_types   = (const int*)d_in[0];
    const int*   edge_index   = (const int*)d_in[1];
    const float* norm_length  = (const float*)d_in[2];
    const float* class_weight = (const float*)d_in[3];
    float*       out          = (float*)d_out;

    const int n_edges   = in_sizes[2];           // |norm_length| = E
    const int* edge_src = edge_index;            // row 0 of [2, E]
    const int* edge_dst = edge_index + n_edges;  // row 1

    const int nchunks = (n_edges + 63) >> 6;
    const int n_pad   = nchunks << 6;

    float* tbl  = (float*)d_ws;                           // 192 KB table
    uint2* meta = (uint2*)((char*)d_ws + (1 << 20));      // 16 MB packed meta

    hipLaunchKernelGGL(build_table_kernel, dim3(64), dim3(256), 0, stream,
                       class_weight, tbl);
    hipLaunchKernelGGL(edge_meta_kernel, dim3(2048), dim3(256), 0, stream,
                       atom_types, edge_src, edge_dst, norm_length,
                       meta, n_edges, n_pad);
    hipLaunchKernelGGL(spline_eval_kernel, dim3(4096), dim3(256), 0, stream,
                       meta, (const float4*)tbl, out, n_edges);
}